// Round 4
// baseline (735.551 us; speedup 1.0000x reference)
//
#include <hip/hip_runtime.h>
#include <math.h>

#define NODES 10000
#define NEDGE 320000
#define INDIM 512
#define CH    128
#define GB1   157   // gemm row-tile blocks (64 rows each)
#define FB    313   // fill blocks
#define CB    1250  // count blocks (1250*256 == 320000 exactly)
#define ZB    2500  // z2 blocks (4 waves each -> 10000 rows)

typedef float f32x4 __attribute__((ext_vector_type(4)));
typedef short s16x8 __attribute__((ext_vector_type(8)));
typedef short s16x4 __attribute__((ext_vector_type(4)));

// bf16 round-to-nearest-even
__device__ __forceinline__ short f2bf(float f) {
    unsigned u = __float_as_uint(f);
    return (short)((u + 0x7fffu + ((u >> 16) & 1u)) >> 16);
}
__device__ __forceinline__ float bf2f(short s) {
    return __uint_as_float(((unsigned)(unsigned short)s) << 16);
}

// ---- split-bf16 MFMA GEMM tile: rows [row0, row0+64) x 128 cols, out = A@W^T (+bias)(opt l2n*1.8)
__device__ __forceinline__ void gemm_tile(const float* __restrict__ A, const float* __restrict__ W,
                                          const float* __restrict__ bias, float* __restrict__ outp,
                                          int M, int K, bool l2n, int row0,
                                          short* Ah, short* Al, short* Bh, short* Bl) {
    const int SROW = 72;
    int tid = threadIdx.x;
    int wave = tid >> 6, lane = tid & 63, quad = lane >> 4, l16 = lane & 15;

    f32x4 acc[8];
#pragma unroll
    for (int t = 0; t < 8; t++) acc[t] = (f32x4){0.f, 0.f, 0.f, 0.f};

    for (int kb = 0; kb < K; kb += 64) {
        __syncthreads();
#pragma unroll
        for (int i = 0; i < 4; i++) {  // A tile: 64 rows x 64 k
            int idx = tid + 256 * i;
            int j = idx & 15, r = idx >> 4;
            float4 v = {0.f, 0.f, 0.f, 0.f};
            int grow = row0 + r;
            if (grow < M) v = *(const float4*)(A + (size_t)grow * K + kb + 4 * j);
            float vv[4] = {v.x, v.y, v.z, v.w};
            s16x4 h4, l4;
#pragma unroll
            for (int q = 0; q < 4; q++) {
                short hs = f2bf(vv[q]);
                h4[q] = hs;
                l4[q] = f2bf(vv[q] - bf2f(hs));
            }
            *(s16x4*)&Ah[r * SROW + 4 * j] = h4;
            *(s16x4*)&Al[r * SROW + 4 * j] = l4;
        }
#pragma unroll
        for (int i = 0; i < 8; i++) {  // B tile: 128 n x 64 k
            int idx = tid + 256 * i;
            int j = idx & 15, n = idx >> 4;
            float4 v = *(const float4*)(W + (size_t)n * K + kb + 4 * j);
            float vv[4] = {v.x, v.y, v.z, v.w};
            s16x4 h4, l4;
#pragma unroll
            for (int q = 0; q < 4; q++) {
                short hs = f2bf(vv[q]);
                h4[q] = hs;
                l4[q] = f2bf(vv[q] - bf2f(hs));
            }
            *(s16x4*)&Bh[n * SROW + 4 * j] = h4;
            *(s16x4*)&Bl[n * SROW + 4 * j] = l4;
        }
        __syncthreads();

#pragma unroll
        for (int kk = 0; kk < 64; kk += 32) {
            int aoff = (wave * 16 + l16) * SROW + kk + quad * 8;
            s16x8 ah = *(const s16x8*)&Ah[aoff];
            s16x8 al = *(const s16x8*)&Al[aoff];
#pragma unroll
            for (int t = 0; t < 8; t++) {
                int boff = (t * 16 + l16) * SROW + kk + quad * 8;
                s16x8 bh = *(const s16x8*)&Bh[boff];
                s16x8 bl = *(const s16x8*)&Bl[boff];
                acc[t] = __builtin_amdgcn_mfma_f32_16x16x32_bf16(ah, bh, acc[t], 0, 0, 0);
                acc[t] = __builtin_amdgcn_mfma_f32_16x16x32_bf16(ah, bl, acc[t], 0, 0, 0);
                acc[t] = __builtin_amdgcn_mfma_f32_16x16x32_bf16(al, bh, acc[t], 0, 0, 0);
            }
        }
    }

    if (bias) {
#pragma unroll
        for (int t = 0; t < 8; t++) {
            float bv = bias[t * 16 + l16];
#pragma unroll
            for (int r = 0; r < 4; r++) acc[t][r] += bv;
        }
    }
    if (l2n) {
#pragma unroll
        for (int r = 0; r < 4; r++) {
            float ss = 0.f;
#pragma unroll
            for (int t = 0; t < 8; t++) ss += acc[t][r] * acc[t][r];
#pragma unroll
            for (int off = 1; off < 16; off <<= 1) ss += __shfl_xor(ss, off, 64);
            float scale = 1.8f / fmaxf(sqrtf(ss), 1e-12f);
#pragma unroll
            for (int t = 0; t < 8; t++) acc[t][r] *= scale;
        }
    }
#pragma unroll
    for (int r = 0; r < 4; r++) {
        int grow = row0 + wave * 16 + quad * 4 + r;
        if (grow < M)
#pragma unroll
            for (int t = 0; t < 8; t++)
                outp[(size_t)grow * CH + t * 16 + l16] = acc[t][r];
    }
}

// ---- M1: zero deg + cursor ----
__global__ __launch_bounds__(256) void k_zero(int* deg, int* cursor) {
    int i = blockIdx.x * 256 + threadIdx.x;
    if (i < NODES) { deg[i] = 0; cursor[i] = 0; }
}

// ---- M2: gemm1 (blocks 0..GB1) + degree count (blocks GB1..GB1+CB) ----
__global__ __launch_bounds__(256) void k_m2(const float* __restrict__ x,
                                            const float* __restrict__ W2,
                                            const float* __restrict__ b2,
                                            const int* __restrict__ ei,
                                            int* deg, float* __restrict__ h) {
    __shared__ __align__(16) char smem[55296];
    int b = blockIdx.x;
    if (b < GB1) {
        gemm_tile(x, W2, b2, h, NODES, INDIM, true, b * 64,
                  (short*)smem, (short*)(smem + 9216), (short*)(smem + 18432), (short*)(smem + 36864));
    } else {
        int e = (b - GB1) * 256 + threadIdx.x;
        if (e < NEDGE) atomicAdd(&deg[ei[NEDGE + e]], 1);
    }
}

// ---- M3: block 0 = scan (1KB LDS), blocks 1..ZB = z2 wave-per-row at full occupancy ----
__global__ __launch_bounds__(256) void k_m3(const int* __restrict__ deg,
                                            int* startArr, float* dinv,
                                            const float* __restrict__ x2,
                                            const float* __restrict__ W22,
                                            float* __restrict__ z2v) {
    if (blockIdx.x == 0) {
        __shared__ int s[256];
        const int CHUNK = 40;  // 256*40 >= 10000
        int t = threadIdx.x;
        int i0 = t * CHUNK;
        int local = 0;
        for (int j = 0; j < CHUNK; j++) {
            int i = i0 + j;
            if (i < NODES) local += deg[i];
        }
        s[t] = local;
        __syncthreads();
        for (int off = 1; off < 256; off <<= 1) {
            int v = (t >= off) ? s[t - off] : 0;
            __syncthreads();
            s[t] += v;
            __syncthreads();
        }
        int run = s[t] - local;  // exclusive prefix
        for (int j = 0; j < CHUNK; j++) {
            int i = i0 + j;
            if (i < NODES) {
                startArr[i] = run;
                run += deg[i];
                dinv[i] = rsqrtf((float)(deg[i] + 1));  // +1 self-loop
            }
        }
        if (t == 255) startArr[NODES] = NEDGE;
    } else {
        int lane = threadIdx.x & 63;
        int row = (blockIdx.x - 1) * 4 + (threadIdx.x >> 6);
        const float4* xr = (const float4*)(x2 + (size_t)row * NODES);
        const float4* w0 = (const float4*)W22;
        const float4* w1 = (const float4*)(W22 + NODES);
        float s0 = 0.f, s1 = 0.f;
        int j = lane;
#pragma unroll 4
        for (int k = 0; k < 39; k++) {  // 39*64 = 2496 of 2500 float4
            float4 v = xr[j];
            float4 a = w0[j];
            float4 c = w1[j];
            s0 += v.x * a.x + v.y * a.y + v.z * a.z + v.w * a.w;
            s1 += v.x * c.x + v.y * c.y + v.z * c.z + v.w * c.w;
            j += 64;
        }
        if (lane < 4) {  // tail
            int jt = 2496 + lane;
            float4 v = xr[jt];
            float4 a = w0[jt];
            float4 c = w1[jt];
            s0 += v.x * a.x + v.y * a.y + v.z * a.z + v.w * a.w;
            s1 += v.x * c.x + v.y * c.y + v.z * c.z + v.w * c.w;
        }
#pragma unroll
        for (int off = 1; off < 64; off <<= 1) {
            s0 += __shfl_xor(s0, off, 64);
            s1 += __shfl_xor(s1, off, 64);
        }
        if (lane == 0) {
            float n = sqrtf(s0 * s0 + s1 * s1);
            z2v[row] = 0.8f * s0 / fmaxf(n, 1e-12f);
        }
    }
}

// ---- M4: gemm2 (blocks 0..GB1) + CSR fill (blocks GB1..GB1+FB) ----
__global__ __launch_bounds__(256) void k_m4(const float* __restrict__ h,
                                            const float* __restrict__ Wg,
                                            const int* __restrict__ ei,
                                            const int* __restrict__ startArr,
                                            int* cursor, int2* pairs,
                                            float* __restrict__ xw) {
    __shared__ __align__(16) char smem[55296];
    int b = blockIdx.x;
    if (b < GB1) {
        gemm_tile(h, Wg, nullptr, xw, NODES, CH, false, b * 64,
                  (short*)smem, (short*)(smem + 9216), (short*)(smem + 18432), (short*)(smem + 36864));
    } else {
        for (int e = (b - GB1) * 256 + threadIdx.x; e < NEDGE; e += FB * 256) {
            int c = ei[NEDGE + e], src = ei[e];
            int pos = atomicAdd(&cursor[c], 1);
            pairs[startArr[c] + pos] = make_int2(src, e);
        }
    }
}

// ---- M5: GCN aggregation, wave-per-node CSR pull ----
__global__ __launch_bounds__(256) void k_agg(const float* __restrict__ xw,
                                             const float* __restrict__ dinv,
                                             const int2* __restrict__ pairs,
                                             const int* __restrict__ startArr,
                                             const float* __restrict__ bg,
                                             float* __restrict__ z1) {
    int node = blockIdx.x * 4 + (threadIdx.x >> 6);
    int lane = threadIdx.x & 63;
    if (node >= NODES) return;
    float di = dinv[node];
    float2 v = *(const float2*)(xw + (size_t)node * CH + 2 * lane);
    float ax = v.x * di * di, ay = v.y * di * di;
    int s = startArr[node], e2 = startArr[node + 1];
    int i = s;
    for (; i + 1 < e2; i += 2) {
        int2 p0 = pairs[i], p1 = pairs[i + 1];
        float c0 = dinv[p0.x] * di, c1 = dinv[p1.x] * di;
        float2 u0 = *(const float2*)(xw + (size_t)p0.x * CH + 2 * lane);
        float2 u1 = *(const float2*)(xw + (size_t)p1.x * CH + 2 * lane);
        ax += u0.x * c0 + u1.x * c1;
        ay += u0.y * c0 + u1.y * c1;
    }
    if (i < e2) {
        int2 p = pairs[i];
        float c0 = dinv[p.x] * di;
        float2 u = *(const float2*)(xw + (size_t)p.x * CH + 2 * lane);
        ax += u.x * c0;
        ay += u.y * c0;
    }
    float2 bgv = *(const float2*)(bg + 2 * lane);
    float2 res = {ax + bgv.x, ay + bgv.y};
    *(float2*)(z1 + (size_t)node * CH + 2 * lane) = res;
}

// ---- M6: edge scoring, wave-per-target-node, z1[c] in registers ----
__global__ __launch_bounds__(256) void k_score(const float* __restrict__ z1,
                                               const float* __restrict__ z2v,
                                               const int2* __restrict__ pairs,
                                               const int* __restrict__ startArr,
                                               float* __restrict__ out) {
    int c = blockIdx.x * 4 + (threadIdx.x >> 6);
    int lane = threadIdx.x & 63;
    if (c >= NODES) return;
    float2 v = *(const float2*)(z1 + (size_t)c * CH + 2 * lane);
    float zc = z2v[c];
    int s = startArr[c], e2 = startArr[c + 1];
    int i = s;
    for (; i + 1 < e2; i += 2) {
        int2 p0 = pairs[i], p1 = pairs[i + 1];
        float2 u0 = *(const float2*)(z1 + (size_t)p0.x * CH + 2 * lane);
        float2 u1 = *(const float2*)(z1 + (size_t)p1.x * CH + 2 * lane);
        float d0 = v.x * u0.x + v.y * u0.y;
        float d1 = v.x * u1.x + v.y * u1.y;
#pragma unroll
        for (int off = 1; off < 64; off <<= 1) {
            d0 += __shfl_xor(d0, off, 64);
            d1 += __shfl_xor(d1, off, 64);
        }
        if (lane == 0) {
            float vn0 = zc + z2v[p0.x], vn1 = zc + z2v[p1.x];
            float sf0 = 1.f / (1.f + __expf(-d0)), sn0 = 1.f / (1.f + __expf(-vn0));
            float sf1 = 1.f / (1.f + __expf(-d1)), sn1 = 1.f / (1.f + __expf(-vn1));
            out[p0.y] = sf0 * sf0 + (1.f - sf0) * sn0;
            out[p1.y] = sf1 * sf1 + (1.f - sf1) * sn1;
        }
    }
    if (i < e2) {
        int2 p = pairs[i];
        float2 u = *(const float2*)(z1 + (size_t)p.x * CH + 2 * lane);
        float d = v.x * u.x + v.y * u.y;
#pragma unroll
        for (int off = 1; off < 64; off <<= 1) d += __shfl_xor(d, off, 64);
        if (lane == 0) {
            float vn = zc + z2v[p.x];
            float sfv = 1.f / (1.f + __expf(-d));
            float snv = 1.f / (1.f + __expf(-vn));
            out[p.y] = sfv * sfv + (1.f - sfv) * snv;
        }
    }
}

extern "C" void kernel_launch(void* const* d_in, const int* in_sizes, int n_in,
                              void* d_out, int out_size, void* d_ws, size_t ws_size,
                              hipStream_t stream) {
    const float* x   = (const float*)d_in[0];
    const float* x2  = (const float*)d_in[1];
    const float* W2  = (const float*)d_in[2];
    const float* b2  = (const float*)d_in[3];
    const float* Wg  = (const float*)d_in[4];
    const float* bg  = (const float*)d_in[5];
    const float* W22 = (const float*)d_in[6];
    const int*   ei  = (const int*)d_in[7];
    float* out = (float*)d_out;

    char* ws = (char*)d_ws;
    size_t off = 0;
    auto alloc = [&](size_t bytes) -> void* {
        void* p = ws + off;
        off = (off + bytes + 255) & ~(size_t)255;
        return p;
    };
    int*   deg      = (int*)alloc(NODES * 4);
    int*   cursor   = (int*)alloc(NODES * 4);
    int*   startArr = (int*)alloc((NODES + 1) * 4);
    float* dinv     = (float*)alloc(NODES * 4);
    int2*  pairs    = (int2*)alloc((size_t)NEDGE * 8);
    float* h        = (float*)alloc((size_t)NODES * CH * 4);
    float* xw       = (float*)alloc((size_t)NODES * CH * 4);
    float* z1       = (float*)alloc((size_t)NODES * CH * 4);
    float* z2v     = (float*)alloc(NODES * 4);

    k_zero<<<(NODES + 255) / 256, 256, 0, stream>>>(deg, cursor);
    k_m2<<<GB1 + CB, 256, 0, stream>>>(x, W2, b2, ei, deg, h);
    k_m3<<<1 + ZB, 256, 0, stream>>>(deg, startArr, dinv, x2, W22, z2v);
    k_m4<<<GB1 + FB, 256, 0, stream>>>(h, Wg, ei, startArr, cursor, pairs, xw);
    k_agg<<<(NODES + 3) / 4, 256, 0, stream>>>(xw, dinv, pairs, startArr, bg, z1);
    k_score<<<(NODES + 3) / 4, 256, 0, stream>>>(z1, z2v, pairs, startArr, out);
}

// Round 5
// 682.691 us; speedup vs baseline: 1.0774x; 1.0774x over previous
//
#include <hip/hip_runtime.h>
#include <math.h>

#define NODES 10000
#define NEDGE 320000
#define INDIM 512
#define CH    128
#define GB1   157   // gemm row-tile blocks (64 rows each)
#define FB    313   // fill blocks
#define ZB    2500  // z2 blocks (4 waves each -> 10000 rows)
#define AB    2500  // agg blocks (4 waves each -> 10000 nodes)
#define SB    2500  // score blocks
#define MAXDEG 96   // ELL row capacity (in-degree lambda=32; P(>96) ~ 1e-19)

typedef float f32x4 __attribute__((ext_vector_type(4)));
typedef short s16x8 __attribute__((ext_vector_type(8)));
typedef short s16x4 __attribute__((ext_vector_type(4)));

__device__ __forceinline__ short f2bf(float f) {
    unsigned u = __float_as_uint(f);
    return (short)((u + 0x7fffu + ((u >> 16) & 1u)) >> 16);
}
__device__ __forceinline__ float bf2f(short s) {
    return __uint_as_float(((unsigned)(unsigned short)s) << 16);
}
__device__ __forceinline__ float sigmoidf(float v) {
    return 1.f / (1.f + __expf(-v));
}

// ---- split-bf16 MFMA GEMM tile: rows [row0, row0+64) x 128 cols, out = A@W^T (+bias)(opt l2n*1.8)
__device__ __forceinline__ void gemm_tile(const float* __restrict__ A, const float* __restrict__ W,
                                          const float* __restrict__ bias, float* __restrict__ outp,
                                          int M, int K, bool l2n, int row0,
                                          short* Ah, short* Al, short* Bh, short* Bl) {
    const int SROW = 72;
    int tid = threadIdx.x;
    int wave = tid >> 6, lane = tid & 63, quad = lane >> 4, l16 = lane & 15;

    f32x4 acc[8];
#pragma unroll
    for (int t = 0; t < 8; t++) acc[t] = (f32x4){0.f, 0.f, 0.f, 0.f};

    for (int kb = 0; kb < K; kb += 64) {
        __syncthreads();
#pragma unroll
        for (int i = 0; i < 4; i++) {  // A tile: 64 rows x 64 k
            int idx = tid + 256 * i;
            int j = idx & 15, r = idx >> 4;
            float4 v = {0.f, 0.f, 0.f, 0.f};
            int grow = row0 + r;
            if (grow < M) v = *(const float4*)(A + (size_t)grow * K + kb + 4 * j);
            float vv[4] = {v.x, v.y, v.z, v.w};
            s16x4 h4, l4;
#pragma unroll
            for (int q = 0; q < 4; q++) {
                short hs = f2bf(vv[q]);
                h4[q] = hs;
                l4[q] = f2bf(vv[q] - bf2f(hs));
            }
            *(s16x4*)&Ah[r * SROW + 4 * j] = h4;
            *(s16x4*)&Al[r * SROW + 4 * j] = l4;
        }
#pragma unroll
        for (int i = 0; i < 8; i++) {  // B tile: 128 n x 64 k
            int idx = tid + 256 * i;
            int j = idx & 15, n = idx >> 4;
            float4 v = *(const float4*)(W + (size_t)n * K + kb + 4 * j);
            float vv[4] = {v.x, v.y, v.z, v.w};
            s16x4 h4, l4;
#pragma unroll
            for (int q = 0; q < 4; q++) {
                short hs = f2bf(vv[q]);
                h4[q] = hs;
                l4[q] = f2bf(vv[q] - bf2f(hs));
            }
            *(s16x4*)&Bh[n * SROW + 4 * j] = h4;
            *(s16x4*)&Bl[n * SROW + 4 * j] = l4;
        }
        __syncthreads();

#pragma unroll
        for (int kk = 0; kk < 64; kk += 32) {
            int aoff = (wave * 16 + l16) * SROW + kk + quad * 8;
            s16x8 ah = *(const s16x8*)&Ah[aoff];
            s16x8 al = *(const s16x8*)&Al[aoff];
#pragma unroll
            for (int t = 0; t < 8; t++) {
                int boff = (t * 16 + l16) * SROW + kk + quad * 8;
                s16x8 bh = *(const s16x8*)&Bh[boff];
                s16x8 bl = *(const s16x8*)&Bl[boff];
                acc[t] = __builtin_amdgcn_mfma_f32_16x16x32_bf16(ah, bh, acc[t], 0, 0, 0);
                acc[t] = __builtin_amdgcn_mfma_f32_16x16x32_bf16(ah, bl, acc[t], 0, 0, 0);
                acc[t] = __builtin_amdgcn_mfma_f32_16x16x32_bf16(al, bh, acc[t], 0, 0, 0);
            }
        }
    }

    if (bias) {
#pragma unroll
        for (int t = 0; t < 8; t++) {
            float bv = bias[t * 16 + l16];
#pragma unroll
            for (int r = 0; r < 4; r++) acc[t][r] += bv;
        }
    }
    if (l2n) {
#pragma unroll
        for (int r = 0; r < 4; r++) {
            float ss = 0.f;
#pragma unroll
            for (int t = 0; t < 8; t++) ss += acc[t][r] * acc[t][r];
#pragma unroll
            for (int off = 1; off < 16; off <<= 1) ss += __shfl_xor(ss, off, 64);
            float scale = 1.8f / fmaxf(sqrtf(ss), 1e-12f);
#pragma unroll
            for (int t = 0; t < 8; t++) acc[t][r] *= scale;
        }
    }
#pragma unroll
    for (int r = 0; r < 4; r++) {
        int grow = row0 + wave * 16 + quad * 4 + r;
        if (grow < M)
#pragma unroll
            for (int t = 0; t < 8; t++)
                outp[(size_t)grow * CH + t * 16 + l16] = acc[t][r];
    }
}

// ---- K1: gemm1 (blocks 0..157) + zero cursor (blocks 157..167) ----
__global__ __launch_bounds__(256) void k1(const float* __restrict__ x,
                                          const float* __restrict__ W2,
                                          const float* __restrict__ b2,
                                          int* cursor, float* __restrict__ h) {
    __shared__ __align__(16) char smem[55296];
    int b = blockIdx.x;
    if (b < GB1) {
        gemm_tile(x, W2, b2, h, NODES, INDIM, true, b * 64,
                  (short*)smem, (short*)(smem + 9216), (short*)(smem + 18432), (short*)(smem + 36864));
    } else {
        int i = (b - GB1) * 256 + threadIdx.x;
        if (i < NODES) cursor[i] = 0;
    }
}

// ---- K2: gemm2 (blocks 0..157) + ELL fill (blocks 157..470) ----
__global__ __launch_bounds__(256) void k2(const float* __restrict__ h,
                                          const float* __restrict__ Wg,
                                          const int* __restrict__ ei,
                                          int* cursor, int2* __restrict__ ell,
                                          float* __restrict__ xw) {
    __shared__ __align__(16) char smem[55296];
    int b = blockIdx.x;
    if (b < GB1) {
        gemm_tile(h, Wg, nullptr, xw, NODES, CH, false, b * 64,
                  (short*)smem, (short*)(smem + 9216), (short*)(smem + 18432), (short*)(smem + 36864));
    } else {
        for (int e = (b - GB1) * 256 + threadIdx.x; e < NEDGE; e += FB * 256) {
            int c = ei[NEDGE + e], src = ei[e];
            int pos = atomicAdd(&cursor[c], 1);
            if (pos < MAXDEG) ell[c * MAXDEG + pos] = make_int2(src, e);
        }
    }
}

// ---- K3: interleaved z2 stream (even blocks) + GCN aggregation (odd blocks) ----
__global__ __launch_bounds__(256) void k3(const float* __restrict__ x2,
                                          const float* __restrict__ W22,
                                          const float* __restrict__ xw,
                                          const int* __restrict__ cursor,
                                          const int2* __restrict__ ell,
                                          const float* __restrict__ bg,
                                          float* __restrict__ z2v,
                                          float* __restrict__ z1) {
    int b = blockIdx.x, tid = threadIdx.x;
    int lane = tid & 63, wv = tid >> 6;
    if ((b & 1) == 0) {
        // ---- z2: wave-per-row ----
        int row = (b >> 1) * 4 + wv;
        const float4* xr = (const float4*)(x2 + (size_t)row * NODES);
        const float4* w0 = (const float4*)W22;
        const float4* w1 = (const float4*)(W22 + NODES);
        float s0 = 0.f, s1 = 0.f;
        int j = lane;
#pragma unroll 4
        for (int k = 0; k < 39; k++) {  // 39*64 = 2496 of 2500 float4
            float4 v = xr[j];
            float4 a = w0[j];
            float4 c = w1[j];
            s0 += v.x * a.x + v.y * a.y + v.z * a.z + v.w * a.w;
            s1 += v.x * c.x + v.y * c.y + v.z * c.z + v.w * c.w;
            j += 64;
        }
        if (lane < 4) {
            int jt = 2496 + lane;
            float4 v = xr[jt];
            float4 a = w0[jt];
            float4 c = w1[jt];
            s0 += v.x * a.x + v.y * a.y + v.z * a.z + v.w * a.w;
            s1 += v.x * c.x + v.y * c.y + v.z * c.z + v.w * c.w;
        }
#pragma unroll
        for (int off = 1; off < 64; off <<= 1) {
            s0 += __shfl_xor(s0, off, 64);
            s1 += __shfl_xor(s1, off, 64);
        }
        if (lane == 0) {
            float n = sqrtf(s0 * s0 + s1 * s1);
            z2v[row] = 0.8f * s0 / fmaxf(n, 1e-12f);
        }
    } else {
        // ---- agg: wave-per-node, 16-lane groups x 4 neighbors per iter ----
        int node = (b >> 1) * 4 + wv;
        int g = lane >> 4, l16 = lane & 15;
        int cnt = cursor[node];
        float di = rsqrtf((float)(cnt + 1));
        float4 a0 = {0.f, 0.f, 0.f, 0.f}, a1 = {0.f, 0.f, 0.f, 0.f};
        const int2* row = ell + node * MAXDEG;
        for (int i = g; i < cnt; i += 4) {
            int2 p = row[i];
            float w = rsqrtf((float)(cursor[p.x] + 1)) * di;
            const float4* u = (const float4*)(xw + (size_t)p.x * CH + l16 * 8);
            float4 u0 = u[0], u1 = u[1];
            a0.x += w * u0.x; a0.y += w * u0.y; a0.z += w * u0.z; a0.w += w * u0.w;
            a1.x += w * u1.x; a1.y += w * u1.y; a1.z += w * u1.z; a1.w += w * u1.w;
        }
        // cross-group reduce (channels identical across groups)
#pragma unroll
        for (int off = 16; off < 64; off <<= 1) {
            a0.x += __shfl_xor(a0.x, off, 64); a0.y += __shfl_xor(a0.y, off, 64);
            a0.z += __shfl_xor(a0.z, off, 64); a0.w += __shfl_xor(a0.w, off, 64);
            a1.x += __shfl_xor(a1.x, off, 64); a1.y += __shfl_xor(a1.y, off, 64);
            a1.z += __shfl_xor(a1.z, off, 64); a1.w += __shfl_xor(a1.w, off, 64);
        }
        if (g == 0) {
            const float4* s = (const float4*)(xw + (size_t)node * CH + l16 * 8);
            const float4* bgp = (const float4*)(bg + l16 * 8);
            float4 s0 = s[0], s1 = s[1], b0 = bgp[0], b1 = bgp[1];
            float sc = di * di;
            a0.x += s0.x * sc + b0.x; a0.y += s0.y * sc + b0.y;
            a0.z += s0.z * sc + b0.z; a0.w += s0.w * sc + b0.w;
            a1.x += s1.x * sc + b1.x; a1.y += s1.y * sc + b1.y;
            a1.z += s1.z * sc + b1.z; a1.w += s1.w * sc + b1.w;
            float4* o = (float4*)(z1 + (size_t)node * CH + l16 * 8);
            o[0] = a0;
            o[1] = a1;
        }
    }
}

// ---- K4: score, wave-per-node, 16-lane groups x 4 edges per iter ----
__global__ __launch_bounds__(256) void k4(const float* __restrict__ z1,
                                          const float* __restrict__ z2v,
                                          const int* __restrict__ cursor,
                                          const int2* __restrict__ ell,
                                          float* __restrict__ out) {
    int node = blockIdx.x * 4 + (threadIdx.x >> 6);
    int lane = threadIdx.x & 63;
    int g = lane >> 4, l16 = lane & 15;
    int cnt = cursor[node];
    float zc = z2v[node];
    const float4* vp = (const float4*)(z1 + (size_t)node * CH + l16 * 8);
    float4 v0 = vp[0], v1 = vp[1];
    const int2* row = ell + node * MAXDEG;
    for (int i = g; i < cnt; i += 4) {
        int2 p = row[i];
        const float4* up = (const float4*)(z1 + (size_t)p.x * CH + l16 * 8);
        float4 u0 = up[0], u1 = up[1];
        float d = v0.x * u0.x + v0.y * u0.y + v0.z * u0.z + v0.w * u0.w
                + v1.x * u1.x + v1.y * u1.y + v1.z * u1.z + v1.w * u1.w;
#pragma unroll
        for (int off = 1; off < 16; off <<= 1) d += __shfl_xor(d, off, 64);
        if (l16 == 0) {
            float sf = sigmoidf(d);
            float sn = sigmoidf(zc + z2v[p.x]);
            out[p.y] = sf * sf + (1.f - sf) * sn;
        }
    }
}

extern "C" void kernel_launch(void* const* d_in, const int* in_sizes, int n_in,
                              void* d_out, int out_size, void* d_ws, size_t ws_size,
                              hipStream_t stream) {
    const float* x   = (const float*)d_in[0];
    const float* x2  = (const float*)d_in[1];
    const float* W2  = (const float*)d_in[2];
    const float* b2  = (const float*)d_in[3];
    const float* Wg  = (const float*)d_in[4];
    const float* bg  = (const float*)d_in[5];
    const float* W22 = (const float*)d_in[6];
    const int*   ei  = (const int*)d_in[7];
    float* out = (float*)d_out;

    char* ws = (char*)d_ws;
    size_t off = 0;
    auto alloc = [&](size_t bytes) -> void* {
        void* p = ws + off;
        off = (off + bytes + 255) & ~(size_t)255;
        return p;
    };
    int*   cursor = (int*)alloc(NODES * 4);
    int2*  ell    = (int2*)alloc((size_t)NODES * MAXDEG * 8);
    float* h      = (float*)alloc((size_t)NODES * CH * 4);
    float* xw     = (float*)alloc((size_t)NODES * CH * 4);
    float* z1     = (float*)alloc((size_t)NODES * CH * 4);
    float* z2v    = (float*)alloc(NODES * 4);

    k1<<<GB1 + 40, 256, 0, stream>>>(x, W2, b2, cursor, h);
    k2<<<GB1 + FB, 256, 0, stream>>>(h, Wg, ei, cursor, ell, xw);
    k3<<<ZB + AB, 256, 0, stream>>>(x2, W22, xw, cursor, ell, bg, z2v, z1);
    k4<<<SB, 256, 0, stream>>>(z1, z2v, cursor, ell, out);
}